// Round 1
// baseline (1873.563 us; speedup 1.0000x reference)
//
#include <hip/hip_runtime.h>
#include <math.h>

#define L_SEQ 2048
#define DMOD  1024
#define DIN   2048
#define NBATCH 2
#define NTOK  (NBATCH * L_SEQ)   // 4096 tokens
#define NST   16
#define RRANK 64

// ---------------------------------------------------------------------------
// Generic fp32 tiled GEMM: C(M,N) = A(M,K) @ B(K,N), row-major, 64x64 tile,
// 256 threads, 4x4 micro-tile per thread. EPI=1: softplus(acc + bias[col]).
// ---------------------------------------------------------------------------
template<int EPI>
__global__ __launch_bounds__(256) void gemm64(
    const float* __restrict__ A, int lda,
    const float* __restrict__ B, int ldb,
    float* __restrict__ C, int ldc,
    int M, int N, int K, const float* __restrict__ bias)
{
    __shared__ float AsT[16][68];   // [k][m], padded
    __shared__ float Bs[16][68];    // [k][n], padded

    const int tid = threadIdx.x;
    const int tx  = tid & 15;       // 0..15 -> 4 cols each
    const int ty  = tid >> 4;       // 0..15 -> 4 rows each
    const int m0  = blockIdx.y * 64;
    const int n0  = blockIdx.x * 64;

    const int ar = tid >> 2;        // 0..63 : A tile row
    const int ak = (tid & 3) * 4;   // 0,4,8,12 : A tile k-offset
    const int bk = tid >> 4;        // 0..15 : B tile k-row
    const int bn = (tid & 15) * 4;  // 0..60 : B tile col-offset

    float acc[4][4] = {};

    for (int k0 = 0; k0 < K; k0 += 16) {
        // global loads to regs
        float4 av = *(const float4*)(A + (size_t)(m0 + ar) * lda + (k0 + ak));
        float4 bv;
        if (n0 + 64 <= N) {
            bv = *(const float4*)(B + (size_t)(k0 + bk) * ldb + (n0 + bn));
        } else {
            bv.x = (n0 + bn + 0 < N) ? B[(size_t)(k0 + bk) * ldb + n0 + bn + 0] : 0.f;
            bv.y = (n0 + bn + 1 < N) ? B[(size_t)(k0 + bk) * ldb + n0 + bn + 1] : 0.f;
            bv.z = (n0 + bn + 2 < N) ? B[(size_t)(k0 + bk) * ldb + n0 + bn + 2] : 0.f;
            bv.w = (n0 + bn + 3 < N) ? B[(size_t)(k0 + bk) * ldb + n0 + bn + 3] : 0.f;
        }
        __syncthreads();   // previous iter's LDS reads complete
        AsT[ak + 0][ar] = av.x;
        AsT[ak + 1][ar] = av.y;
        AsT[ak + 2][ar] = av.z;
        AsT[ak + 3][ar] = av.w;
        *(float4*)&Bs[bk][bn] = bv;
        __syncthreads();

        #pragma unroll
        for (int kk = 0; kk < 16; ++kk) {
            float4 a = *(const float4*)&AsT[kk][ty * 4];
            float4 b = *(const float4*)&Bs[kk][tx * 4];
            float aa[4] = {a.x, a.y, a.z, a.w};
            float bb[4] = {b.x, b.y, b.z, b.w};
            #pragma unroll
            for (int i = 0; i < 4; ++i)
                #pragma unroll
                for (int j = 0; j < 4; ++j)
                    acc[i][j] += aa[i] * bb[j];
        }
    }

    #pragma unroll
    for (int i = 0; i < 4; ++i) {
        int row = m0 + ty * 4 + i;
        #pragma unroll
        for (int j = 0; j < 4; ++j) {
            int col = n0 + tx * 4 + j;
            if (col < N) {
                float v = acc[i][j];
                if (EPI == 1) {
                    v += bias[col];
                    v = (v > 20.f) ? v : log1pf(expf(v));  // softplus
                }
                C[(size_t)row * ldc + col] = v;
            }
        }
    }
}

// ---------------------------------------------------------------------------
// Causal depthwise conv (K=4) + SiLU. u lives in the first DIN columns of xz.
// ---------------------------------------------------------------------------
__global__ __launch_bounds__(256) void conv_silu_k(
    const float* __restrict__ xz, const float* __restrict__ w_conv,
    const float* __restrict__ b_conv, float* __restrict__ uconv)
{
    int idx   = blockIdx.x * 256 + threadIdx.x;   // over NTOK*DIN
    int d     = idx & (DIN - 1);
    int token = idx >> 11;                        // DIN = 2048
    int t     = token & (L_SEQ - 1);

    float acc = b_conv[d];
    #pragma unroll
    for (int k = 0; k < 4; ++k) {
        int tt = t - 3 + k;
        if (tt >= 0)
            acc += xz[(size_t)(token - 3 + k) * 4096 + d] * w_conv[d * 4 + k];
    }
    float s = acc / (1.f + expf(-acc));  // silu
    uconv[(size_t)token * DIN + d] = s;
}

// ---------------------------------------------------------------------------
// Sequential selective scan. One thread per (b,d); h[16] in registers.
// delta comes from xz[:, 0:2048] (GEMM3 wrote it there), z from xz[:, 2048:].
// Writes y_final in place over uconv.
// ---------------------------------------------------------------------------
#define SCHUNK 32
__global__ __launch_bounds__(64) void scan_k(
    const float* __restrict__ xz,
    float* __restrict__ uconv,
    const float* __restrict__ dbc,
    const float* __restrict__ A_log,
    const float* __restrict__ Dp)
{
    int b   = blockIdx.x >> 5;          // 64 blocks: 2 batches x 32 d-groups
    int d0  = (blockIdx.x & 31) << 6;   // 64 channels per block
    int tid = threadIdx.x;
    int d   = d0 + tid;

    __shared__ float sDelta[SCHUNK][64];
    __shared__ float sU[SCHUNK][64];
    __shared__ float sZ[SCHUNK][64];
    __shared__ float sBC[SCHUNK][32];   // [s][0:16]=B, [s][16:32]=C

    float An[NST];
    #pragma unroll
    for (int n = 0; n < NST; ++n) An[n] = -expf(A_log[(size_t)d * NST + n]);
    float Dd = Dp[d];

    float h[NST];
    #pragma unroll
    for (int n = 0; n < NST; ++n) h[n] = 0.f;

    const size_t tokbase = (size_t)b * L_SEQ;

    for (int t0 = 0; t0 < L_SEQ; t0 += SCHUNK) {
        __syncthreads();
        #pragma unroll
        for (int i = 0; i < SCHUNK; ++i) {
            size_t tok = tokbase + t0 + i;
            sDelta[i][tid] = xz[tok * 4096 + d0 + tid];
            sU[i][tid]     = uconv[tok * 2048 + d0 + tid];
            sZ[i][tid]     = xz[tok * 4096 + 2048 + d0 + tid];
        }
        #pragma unroll
        for (int i = 0; i < SCHUNK / 2; ++i) {  // 1024 floats / 64 thr
            int e = i * 64 + tid;
            int s = e >> 5, c = e & 31;
            sBC[s][c] = dbc[(tokbase + t0 + s) * 96 + 64 + c];
        }
        __syncthreads();

        for (int s = 0; s < SCHUNK; ++s) {
            float delta = sDelta[s][tid];
            float u     = sU[s][tid];
            float du    = delta * u;
            float bc[32];
            #pragma unroll
            for (int q = 0; q < 8; ++q)
                *(float4*)&bc[q * 4] = ((const float4*)sBC[s])[q];
            float y = 0.f;
            #pragma unroll
            for (int n = 0; n < NST; ++n) {
                float dA = __expf(delta * An[n]);
                h[n] = h[n] * dA + du * bc[n];
                y += h[n] * bc[16 + n];
            }
            float z  = sZ[s][tid];
            float sz = z / (1.f + __expf(-z));
            uconv[(tokbase + t0 + s) * 2048 + d] = (y + u * Dd) * sz;
        }
    }
}

// ---------------------------------------------------------------------------
// LayerNorm over DM + residual. One block per row.
// ---------------------------------------------------------------------------
__global__ __launch_bounds__(256) void ln_k(
    const float* __restrict__ outpre, const float* __restrict__ x,
    const float* __restrict__ gamma, const float* __restrict__ beta,
    float* __restrict__ out)
{
    int row = blockIdx.x;
    int tid = threadIdx.x;
    const float* rp = outpre + (size_t)row * DMOD;
    float4 v = ((const float4*)rp)[tid];

    float s  = v.x + v.y + v.z + v.w;
    float s2 = v.x * v.x + v.y * v.y + v.z * v.z + v.w * v.w;
    #pragma unroll
    for (int off = 32; off > 0; off >>= 1) {
        s  += __shfl_down(s, off);
        s2 += __shfl_down(s2, off);
    }
    __shared__ float ws[4], ws2[4];
    int wave = tid >> 6, lane = tid & 63;
    if (lane == 0) { ws[wave] = s; ws2[wave] = s2; }
    __syncthreads();
    if (tid == 0) {
        float ts = 0.f, ts2 = 0.f;
        #pragma unroll
        for (int w = 0; w < 4; ++w) { ts += ws[w]; ts2 += ws2[w]; }
        ws[0] = ts; ws2[0] = ts2;
    }
    __syncthreads();
    float mu  = ws[0] * (1.f / DMOD);
    float var = ws2[0] * (1.f / DMOD) - mu * mu;
    float rs  = rsqrtf(var + 1e-5f);

    float4 g  = ((const float4*)gamma)[tid];
    float4 be = ((const float4*)beta)[tid];
    float4 xr = ((const float4*)(x + (size_t)row * DMOD))[tid];
    float4 o;
    o.x = (v.x - mu) * rs * g.x + be.x + xr.x;
    o.y = (v.y - mu) * rs * g.y + be.y + xr.y;
    o.z = (v.z - mu) * rs * g.z + be.z + xr.z;
    o.w = (v.w - mu) * rs * g.w + be.w + xr.w;
    ((float4*)(out + (size_t)row * DMOD))[tid] = o;
}

// ---------------------------------------------------------------------------
extern "C" void kernel_launch(void* const* d_in, const int* in_sizes, int n_in,
                              void* d_out, int out_size, void* d_ws, size_t ws_size,
                              hipStream_t stream)
{
    const float* x      = (const float*)d_in[0];
    const float* W_in   = (const float*)d_in[1];
    const float* w_conv = (const float*)d_in[2];
    const float* b_conv = (const float*)d_in[3];
    const float* W_x    = (const float*)d_in[4];
    const float* W_dt   = (const float*)d_in[5];
    const float* b_dt   = (const float*)d_in[6];
    const float* A_log  = (const float*)d_in[7];
    const float* Dp     = (const float*)d_in[8];
    const float* W_out  = (const float*)d_in[9];
    const float* gamma  = (const float*)d_in[10];
    const float* beta   = (const float*)d_in[11];
    float* out = (float*)d_out;

    char* ws = (char*)d_ws;
    float* xz     = (float*)(ws);                               // 4096x4096 (64 MB)
    float* uconv  = (float*)(ws + (size_t)64 * 1024 * 1024);    // 4096x2048 (32 MB)
    float* dbc    = (float*)(ws + (size_t)96 * 1024 * 1024);    // 4096x96  (1.5 MB)
    float* outpre = (float*)(ws + (size_t)98 * 1024 * 1024);    // 4096x1024 (16 MB)

    dim3 blk(256);

    // 1. xz = x @ W_in                       (4096,1024)@(1024,4096)
    gemm64<0><<<dim3(64, 64), blk, 0, stream>>>(x, 1024, W_in, 4096, xz, 4096,
                                                4096, 4096, 1024, nullptr);
    // 2. u = silu(causal_conv(u))            -> uconv
    conv_silu_k<<<dim3(NTOK * DIN / 256), blk, 0, stream>>>(xz, w_conv, b_conv, uconv);
    // 3. dbc = u @ W_x                       (4096,2048)@(2048,96)
    gemm64<0><<<dim3(2, 64), blk, 0, stream>>>(uconv, 2048, W_x, 96, dbc, 96,
                                               4096, 96, 2048, nullptr);
    // 4. delta = softplus(dt @ W_dt + b_dt)  (4096,64)@(64,2048) -> u-half of xz
    gemm64<1><<<dim3(32, 64), blk, 0, stream>>>(dbc, 96, W_dt, 2048, xz, 4096,
                                                4096, 2048, 64, b_dt);
    // 5. selective scan + gate epilogue      -> y overwrites uconv
    scan_k<<<dim3(64), dim3(64), 0, stream>>>(xz, uconv, dbc, A_log, Dp);
    // 6. out_pre = y @ W_out                 (4096,2048)@(2048,1024)
    gemm64<0><<<dim3(16, 64), blk, 0, stream>>>(uconv, 2048, W_out, 1024, outpre, 1024,
                                                4096, 1024, 2048, nullptr);
    // 7. LayerNorm + residual                -> d_out
    ln_k<<<dim3(NTOK), blk, 0, stream>>>(outpre, x, gamma, beta, out);
}

// Round 2
// 1145.324 us; speedup vs baseline: 1.6358x; 1.6358x over previous
//
#include <hip/hip_runtime.h>
#include <math.h>

#define L_SEQ 2048
#define DMOD  1024
#define DIN   2048
#define NBATCH 2
#define NTOK  (NBATCH * L_SEQ)   // 4096 tokens
#define NST   16
#define RRANK 64

#define GCHUNK 32                 // chunks along L
#define CLEN   (L_SEQ / GCHUNK)   // 64 steps per chunk
#define SCHUNK 16                 // LDS staging depth

// ---------------------------------------------------------------------------
// Generic fp32 tiled GEMM: C(M,N) = A(M,K) @ B(K,N), row-major, 64x64 tile,
// 256 threads, 4x4 micro-tile per thread. EPI=1: softplus(acc + bias[col]).
// ---------------------------------------------------------------------------
template<int EPI>
__global__ __launch_bounds__(256) void gemm64(
    const float* __restrict__ A, int lda,
    const float* __restrict__ B, int ldb,
    float* __restrict__ C, int ldc,
    int M, int N, int K, const float* __restrict__ bias)
{
    __shared__ float AsT[16][68];   // [k][m], padded
    __shared__ float Bs[16][68];    // [k][n], padded

    const int tid = threadIdx.x;
    const int tx  = tid & 15;
    const int ty  = tid >> 4;
    const int m0  = blockIdx.y * 64;
    const int n0  = blockIdx.x * 64;

    const int ar = tid >> 2;
    const int ak = (tid & 3) * 4;
    const int bk = tid >> 4;
    const int bn = (tid & 15) * 4;

    float acc[4][4] = {};

    for (int k0 = 0; k0 < K; k0 += 16) {
        float4 av = *(const float4*)(A + (size_t)(m0 + ar) * lda + (k0 + ak));
        float4 bv;
        if (n0 + 64 <= N) {
            bv = *(const float4*)(B + (size_t)(k0 + bk) * ldb + (n0 + bn));
        } else {
            bv.x = (n0 + bn + 0 < N) ? B[(size_t)(k0 + bk) * ldb + n0 + bn + 0] : 0.f;
            bv.y = (n0 + bn + 1 < N) ? B[(size_t)(k0 + bk) * ldb + n0 + bn + 1] : 0.f;
            bv.z = (n0 + bn + 2 < N) ? B[(size_t)(k0 + bk) * ldb + n0 + bn + 2] : 0.f;
            bv.w = (n0 + bn + 3 < N) ? B[(size_t)(k0 + bk) * ldb + n0 + bn + 3] : 0.f;
        }
        __syncthreads();
        AsT[ak + 0][ar] = av.x;
        AsT[ak + 1][ar] = av.y;
        AsT[ak + 2][ar] = av.z;
        AsT[ak + 3][ar] = av.w;
        *(float4*)&Bs[bk][bn] = bv;
        __syncthreads();

        #pragma unroll
        for (int kk = 0; kk < 16; ++kk) {
            float4 a = *(const float4*)&AsT[kk][ty * 4];
            float4 b = *(const float4*)&Bs[kk][tx * 4];
            float aa[4] = {a.x, a.y, a.z, a.w};
            float bb[4] = {b.x, b.y, b.z, b.w};
            #pragma unroll
            for (int i = 0; i < 4; ++i)
                #pragma unroll
                for (int j = 0; j < 4; ++j)
                    acc[i][j] += aa[i] * bb[j];
        }
    }

    #pragma unroll
    for (int i = 0; i < 4; ++i) {
        int row = m0 + ty * 4 + i;
        #pragma unroll
        for (int j = 0; j < 4; ++j) {
            int col = n0 + tx * 4 + j;
            if (col < N) {
                float v = acc[i][j];
                if (EPI == 1) {
                    v += bias[col];
                    v = (v > 20.f) ? v : log1pf(expf(v));  // softplus
                }
                C[(size_t)row * ldc + col] = v;
            }
        }
    }
}

// ---------------------------------------------------------------------------
// Causal depthwise conv (K=4) + SiLU.
// ---------------------------------------------------------------------------
__global__ __launch_bounds__(256) void conv_silu_k(
    const float* __restrict__ xz, const float* __restrict__ w_conv,
    const float* __restrict__ b_conv, float* __restrict__ uconv)
{
    int idx   = blockIdx.x * 256 + threadIdx.x;
    int d     = idx & (DIN - 1);
    int token = idx >> 11;
    int t     = token & (L_SEQ - 1);

    float acc = b_conv[d];
    #pragma unroll
    for (int k = 0; k < 4; ++k) {
        int tt = t - 3 + k;
        if (tt >= 0)
            acc += xz[(size_t)(token - 3 + k) * 4096 + d] * w_conv[d * 4 + k];
    }
    float s = acc / (1.f + expf(-acc));
    uconv[(size_t)token * DIN + d] = s;
}

// ---------------------------------------------------------------------------
// Chunked selective scan, pass 1: per (b, dgroup, chunk) run the 64-step
// recurrence from h=0. Emits c[b,d,ch,n] (inhomogeneous term) and
// Dsum[b,d,ch] (sum of delta over chunk).
// Grid: 2 b x 32 dgroups x 32 chunks = 2048 blocks x 64 threads.
// ---------------------------------------------------------------------------
__global__ __launch_bounds__(64) void scan_part1(
    const float* __restrict__ xz,      // delta in cols 0:2048
    const float* __restrict__ uconv,
    const float* __restrict__ dbc,
    const float* __restrict__ A_log,
    float* __restrict__ c_out,         // [2,2048,32,16]
    float* __restrict__ dsum_out)      // [2,2048,32]
{
    int chunk = blockIdx.x & 31;
    int dg    = (blockIdx.x >> 5) & 31;
    int b     = blockIdx.x >> 10;
    int tid   = threadIdx.x;
    int d     = dg * 64 + tid;

    __shared__ float sDelta[SCHUNK][64];
    __shared__ float sU[SCHUNK][64];
    __shared__ float sB[SCHUNK][16];

    float An[NST];
    #pragma unroll
    for (int n = 0; n < NST; ++n) An[n] = -expf(A_log[(size_t)d * NST + n]);

    float h[NST];
    #pragma unroll
    for (int n = 0; n < NST; ++n) h[n] = 0.f;
    float dsum = 0.f;

    const size_t tokbase = (size_t)b * L_SEQ + (size_t)chunk * CLEN;

    for (int t0 = 0; t0 < CLEN; t0 += SCHUNK) {
        __syncthreads();
        #pragma unroll
        for (int i = 0; i < SCHUNK; ++i) {
            size_t tok = tokbase + t0 + i;
            sDelta[i][tid] = xz[tok * 4096 + dg * 64 + tid];
            sU[i][tid]     = uconv[tok * 2048 + dg * 64 + tid];
        }
        #pragma unroll
        for (int i = 0; i < SCHUNK * 16 / 64; ++i) {   // 256 floats / 64 thr
            int e = i * 64 + tid;
            int s = e >> 4, n = e & 15;
            sB[s][n] = dbc[(tokbase + t0 + s) * 96 + RRANK + n];
        }
        __syncthreads();

        #pragma unroll 4
        for (int s = 0; s < SCHUNK; ++s) {
            float delta = sDelta[s][tid];
            float u     = sU[s][tid];
            float du    = delta * u;
            dsum += delta;
            float bv[NST];
            #pragma unroll
            for (int q = 0; q < 4; ++q)
                *(float4*)&bv[q * 4] = ((const float4*)sB[s])[q];
            #pragma unroll
            for (int n = 0; n < NST; ++n)
                h[n] = h[n] * __expf(delta * An[n]) + du * bv[n];
        }
    }

    size_t base = (((size_t)b * DIN + d) * GCHUNK + chunk) * NST;
    #pragma unroll
    for (int q = 0; q < 4; ++q)
        *(float4*)&c_out[base + q * 4] = make_float4(h[q*4], h[q*4+1], h[q*4+2], h[q*4+3]);
    dsum_out[((size_t)b * DIN + d) * GCHUNK + chunk] = dsum;
}

// ---------------------------------------------------------------------------
// Pass 2: per (b,d,n) scan the 32 chunk summaries -> h_start per chunk.
// 65536 threads.
// ---------------------------------------------------------------------------
__global__ __launch_bounds__(256) void scan_part2(
    const float* __restrict__ c_in,     // [2,2048,32,16]
    const float* __restrict__ dsum_in,  // [2,2048,32]
    const float* __restrict__ A_log,
    float* __restrict__ h_start)        // [2,2048,32,16]
{
    int idx = blockIdx.x * 256 + threadIdx.x;
    int n   = idx & 15;
    int d   = (idx >> 4) & (DIN - 1);
    int b   = idx >> 15;

    float An = -expf(A_log[(size_t)d * NST + n]);
    size_t cb = ((size_t)b * DIN + d) * GCHUNK;

    float h = 0.f;
    for (int ch = 0; ch < GCHUNK; ++ch) {
        h_start[(cb + ch) * NST + n] = h;
        float dA = __expf(An * dsum_in[cb + ch]);
        h = h * dA + c_in[(cb + ch) * NST + n];
    }
}

// ---------------------------------------------------------------------------
// Pass 3: re-run each chunk from h_start, compute y + gating epilogue.
// Writes y over uconv. Same grid as pass 1.
// ---------------------------------------------------------------------------
__global__ __launch_bounds__(64) void scan_part3(
    const float* __restrict__ xz,       // delta cols 0:2048, z cols 2048:4096
    float* __restrict__ uconv,          // in: u, out: y
    const float* __restrict__ dbc,
    const float* __restrict__ A_log,
    const float* __restrict__ Dp,
    const float* __restrict__ h_start)
{
    int chunk = blockIdx.x & 31;
    int dg    = (blockIdx.x >> 5) & 31;
    int b     = blockIdx.x >> 10;
    int tid   = threadIdx.x;
    int d     = dg * 64 + tid;

    __shared__ float sDelta[SCHUNK][64];
    __shared__ float sU[SCHUNK][64];
    __shared__ float sZ[SCHUNK][64];
    __shared__ float sBC[SCHUNK][32];   // [s][0:16]=B, [s][16:32]=C

    float An[NST];
    #pragma unroll
    for (int n = 0; n < NST; ++n) An[n] = -expf(A_log[(size_t)d * NST + n]);
    float Dd = Dp[d];

    float h[NST];
    size_t hb = (((size_t)b * DIN + d) * GCHUNK + chunk) * NST;
    #pragma unroll
    for (int q = 0; q < 4; ++q) {
        float4 v = *(const float4*)&h_start[hb + q * 4];
        h[q*4] = v.x; h[q*4+1] = v.y; h[q*4+2] = v.z; h[q*4+3] = v.w;
    }

    const size_t tokbase = (size_t)b * L_SEQ + (size_t)chunk * CLEN;

    for (int t0 = 0; t0 < CLEN; t0 += SCHUNK) {
        __syncthreads();
        #pragma unroll
        for (int i = 0; i < SCHUNK; ++i) {
            size_t tok = tokbase + t0 + i;
            sDelta[i][tid] = xz[tok * 4096 + dg * 64 + tid];
            sU[i][tid]     = uconv[tok * 2048 + dg * 64 + tid];
            sZ[i][tid]     = xz[tok * 4096 + 2048 + dg * 64 + tid];
        }
        #pragma unroll
        for (int i = 0; i < SCHUNK * 32 / 64; ++i) {   // 512 floats / 64 thr
            int e = i * 64 + tid;
            int s = e >> 5, cc = e & 31;
            sBC[s][cc] = dbc[(tokbase + t0 + s) * 96 + RRANK + cc];
        }
        __syncthreads();

        for (int s = 0; s < SCHUNK; ++s) {
            float delta = sDelta[s][tid];
            float u     = sU[s][tid];
            float du    = delta * u;
            float bc[32];
            #pragma unroll
            for (int q = 0; q < 8; ++q)
                *(float4*)&bc[q * 4] = ((const float4*)sBC[s])[q];
            float y = 0.f;
            #pragma unroll
            for (int n = 0; n < NST; ++n) {
                float dA = __expf(delta * An[n]);
                h[n] = h[n] * dA + du * bc[n];
                y += h[n] * bc[16 + n];
            }
            float z  = sZ[s][tid];
            float sz = z / (1.f + __expf(-z));
            uconv[(tokbase + t0 + s) * 2048 + d] = (y + u * Dd) * sz;
        }
    }
}

// ---------------------------------------------------------------------------
// LayerNorm over DM + residual. One block per row.
// ---------------------------------------------------------------------------
__global__ __launch_bounds__(256) void ln_k(
    const float* __restrict__ outpre, const float* __restrict__ x,
    const float* __restrict__ gamma, const float* __restrict__ beta,
    float* __restrict__ out)
{
    int row = blockIdx.x;
    int tid = threadIdx.x;
    const float* rp = outpre + (size_t)row * DMOD;
    float4 v = ((const float4*)rp)[tid];

    float s  = v.x + v.y + v.z + v.w;
    float s2 = v.x * v.x + v.y * v.y + v.z * v.z + v.w * v.w;
    #pragma unroll
    for (int off = 32; off > 0; off >>= 1) {
        s  += __shfl_down(s, off);
        s2 += __shfl_down(s2, off);
    }
    __shared__ float ws[4], ws2[4];
    int wave = tid >> 6, lane = tid & 63;
    if (lane == 0) { ws[wave] = s; ws2[wave] = s2; }
    __syncthreads();
    if (tid == 0) {
        float ts = 0.f, ts2 = 0.f;
        #pragma unroll
        for (int w = 0; w < 4; ++w) { ts += ws[w]; ts2 += ws2[w]; }
        ws[0] = ts; ws2[0] = ts2;
    }
    __syncthreads();
    float mu  = ws[0] * (1.f / DMOD);
    float var = ws2[0] * (1.f / DMOD) - mu * mu;
    float rs  = rsqrtf(var + 1e-5f);

    float4 g  = ((const float4*)gamma)[tid];
    float4 be = ((const float4*)beta)[tid];
    float4 xr = ((const float4*)(x + (size_t)row * DMOD))[tid];
    float4 o;
    o.x = (v.x - mu) * rs * g.x + be.x + xr.x;
    o.y = (v.y - mu) * rs * g.y + be.y + xr.y;
    o.z = (v.z - mu) * rs * g.z + be.z + xr.z;
    o.w = (v.w - mu) * rs * g.w + be.w + xr.w;
    ((float4*)(out + (size_t)row * DMOD))[tid] = o;
}

// ---------------------------------------------------------------------------
extern "C" void kernel_launch(void* const* d_in, const int* in_sizes, int n_in,
                              void* d_out, int out_size, void* d_ws, size_t ws_size,
                              hipStream_t stream)
{
    const float* x      = (const float*)d_in[0];
    const float* W_in   = (const float*)d_in[1];
    const float* w_conv = (const float*)d_in[2];
    const float* b_conv = (const float*)d_in[3];
    const float* W_x    = (const float*)d_in[4];
    const float* W_dt   = (const float*)d_in[5];
    const float* b_dt   = (const float*)d_in[6];
    const float* A_log  = (const float*)d_in[7];
    const float* Dp     = (const float*)d_in[8];
    const float* W_out  = (const float*)d_in[9];
    const float* gamma  = (const float*)d_in[10];
    const float* beta   = (const float*)d_in[11];
    float* out = (float*)d_out;

    char* ws = (char*)d_ws;
    const size_t MB = 1024 * 1024;
    float* xz     = (float*)(ws);                  // 4096x4096 (64 MB)
    float* uconv  = (float*)(ws + 64 * MB);        // 4096x2048 (32 MB)
    float* dbc    = (float*)(ws + 96 * MB);        // 4096x96   (1.5 MB)
    float* dsum   = (float*)(ws + (97 * MB + 512 * 1024)); // 2x2048x32 (0.5 MB)
    float* c_buf  = (float*)(ws + 98 * MB);        // 2x2048x32x16 (8 MB) — overlays outpre region pre-GEMM4
    float* hstart = (float*)(ws + 106 * MB);       // 2x2048x32x16 (8 MB)
    float* outpre = (float*)(ws + 98 * MB);        // 4096x1024 (16 MB) — reused after scan

    dim3 blk(256);

    // 1. xz = x @ W_in
    gemm64<0><<<dim3(64, 64), blk, 0, stream>>>(x, 1024, W_in, 4096, xz, 4096,
                                                4096, 4096, 1024, nullptr);
    // 2. u = silu(causal_conv(u)) -> uconv
    conv_silu_k<<<dim3(NTOK * DIN / 256), blk, 0, stream>>>(xz, w_conv, b_conv, uconv);
    // 3. dbc = u @ W_x
    gemm64<0><<<dim3(2, 64), blk, 0, stream>>>(uconv, 2048, W_x, 96, dbc, 96,
                                               4096, 96, 2048, nullptr);
    // 4. delta = softplus(dt @ W_dt + b_dt) -> u-half of xz
    gemm64<1><<<dim3(32, 64), blk, 0, stream>>>(dbc, 96, W_dt, 2048, xz, 4096,
                                                4096, 2048, 64, b_dt);
    // 5. chunked selective scan (3 passes) -> y overwrites uconv
    scan_part1<<<dim3(NBATCH * 32 * GCHUNK), dim3(64), 0, stream>>>(
        xz, uconv, dbc, A_log, c_buf, dsum);
    scan_part2<<<dim3(NBATCH * DIN * NST / 256), blk, 0, stream>>>(
        c_buf, dsum, A_log, hstart);
    scan_part3<<<dim3(NBATCH * 32 * GCHUNK), dim3(64), 0, stream>>>(
        xz, uconv, dbc, A_log, Dp, hstart);
    // 6. out_pre = y @ W_out
    gemm64<0><<<dim3(16, 64), blk, 0, stream>>>(uconv, 2048, W_out, 1024, outpre, 1024,
                                                4096, 1024, 2048, nullptr);
    // 7. LayerNorm + residual
    ln_k<<<dim3(NTOK), blk, 0, stream>>>(outpre, x, gamma, beta, out);
}

// Round 3
// 563.058 us; speedup vs baseline: 3.3275x; 2.0341x over previous
//
#include <hip/hip_runtime.h>
#include <math.h>

#define L_SEQ 2048
#define DMOD  1024
#define DIN   2048
#define NBATCH 2
#define NTOK  (NBATCH * L_SEQ)   // 4096 tokens
#define NST   16
#define RRANK 64

#define GCHUNK 32                 // chunks along L
#define CLEN   (L_SEQ / GCHUNK)   // 64 steps per chunk
#define SCHUNK 16                 // LDS staging depth

typedef __attribute__((ext_vector_type(8))) short  short8;   // 8 bf16
typedef __attribute__((ext_vector_type(4))) float  f32x4;

// round-to-nearest-even fp32 -> bf16
__device__ __forceinline__ ushort f2bf(float f) {
    unsigned u = __float_as_uint(f);
    u += 0x7fffu + ((u >> 16) & 1u);
    return (ushort)(u >> 16);
}

// ---------------------------------------------------------------------------
// Flat cast fp32 -> bf16, 8 elements/thread.
// ---------------------------------------------------------------------------
__global__ __launch_bounds__(256) void cast_bf16_k(
    const float* __restrict__ src, ushort* __restrict__ dst)
{
    int i = (blockIdx.x * 256 + threadIdx.x) * 8;
    float4 a = *(const float4*)(src + i);
    float4 b = *(const float4*)(src + i + 4);
    ushort4 o0 = make_ushort4(f2bf(a.x), f2bf(a.y), f2bf(a.z), f2bf(a.w));
    ushort4 o1 = make_ushort4(f2bf(b.x), f2bf(b.y), f2bf(b.z), f2bf(b.w));
    *(ushort4*)(dst + i)     = o0;
    *(ushort4*)(dst + i + 4) = o1;
}

// ---------------------------------------------------------------------------
// Transpose + cast: src fp32 [R][C] -> dst bf16 [C][R]. 32x32 LDS tile.
// ---------------------------------------------------------------------------
__global__ __launch_bounds__(256) void tcast_k(
    const float* __restrict__ src, ushort* __restrict__ dst, int R, int C)
{
    __shared__ float t[32][33];
    int tx  = threadIdx.x & 31;
    int ty  = threadIdx.x >> 5;        // 0..7
    int c0  = blockIdx.x * 32;
    int r0  = blockIdx.y * 32;
    #pragma unroll
    for (int i = 0; i < 4; ++i)
        t[ty + i * 8][tx] = src[(size_t)(r0 + ty + i * 8) * C + c0 + tx];
    __syncthreads();
    #pragma unroll
    for (int i = 0; i < 4; ++i)
        dst[(size_t)(c0 + ty + i * 8) * R + r0 + tx] = f2bf(t[tx][ty + i * 8]);
}

// ---------------------------------------------------------------------------
// bf16 MFMA GEMM: C(M,N) fp32 = A(M,K) @ Bt(N,K)^T, 128x128 tile, BK=32,
// 256 threads = 4 waves, each wave 64x64 via 4x4 grid of 16x16x32 MFMAs.
// Requires M%128==0, N%128==0, K%32==0.
// ---------------------------------------------------------------------------
#define LDK 40   // padded halfs per LDS row (80 B: 16B-aligned, 2-way banks = free)
__global__ __launch_bounds__(256) void gemm_mfma(
    const ushort* __restrict__ A,   // [M][K] bf16
    const ushort* __restrict__ Bt,  // [N][K] bf16
    float* __restrict__ C,          // [M][N] fp32
    int M, int N, int K)
{
    __shared__ ushort As[128 * LDK];
    __shared__ ushort Bs[128 * LDK];

    const int tid  = threadIdx.x;
    const int wave = tid >> 6;
    const int lane = tid & 63;
    const int wm   = (wave & 1) * 64;
    const int wn   = (wave >> 1) * 64;
    const int m0   = blockIdx.y * 128;
    const int n0   = blockIdx.x * 128;

    const int srow  = tid >> 2;         // 0..63
    const int skoff = (tid & 3) * 8;    // 0,8,16,24 halfs

    f32x4 acc[4][4];
    #pragma unroll
    for (int i = 0; i < 4; ++i)
        #pragma unroll
        for (int j = 0; j < 4; ++j)
            acc[i][j] = (f32x4){0.f, 0.f, 0.f, 0.f};

    const int lrow = lane & 15;
    const int kq   = (lane >> 4) * 8;

    for (int k0 = 0; k0 < K; k0 += 32) {
        uint4 a0 = *(const uint4*)(A  + (size_t)(m0 + srow)      * K + k0 + skoff);
        uint4 a1 = *(const uint4*)(A  + (size_t)(m0 + 64 + srow) * K + k0 + skoff);
        uint4 b0 = *(const uint4*)(Bt + (size_t)(n0 + srow)      * K + k0 + skoff);
        uint4 b1 = *(const uint4*)(Bt + (size_t)(n0 + 64 + srow) * K + k0 + skoff);
        __syncthreads();
        *(uint4*)&As[(srow)      * LDK + skoff] = a0;
        *(uint4*)&As[(64 + srow) * LDK + skoff] = a1;
        *(uint4*)&Bs[(srow)      * LDK + skoff] = b0;
        *(uint4*)&Bs[(64 + srow) * LDK + skoff] = b1;
        __syncthreads();

        short8 af[4], bfr[4];
        #pragma unroll
        for (int i = 0; i < 4; ++i) {
            af[i]  = *(const short8*)&As[(wm + i * 16 + lrow) * LDK + kq];
            bfr[i] = *(const short8*)&Bs[(wn + i * 16 + lrow) * LDK + kq];
        }
        #pragma unroll
        for (int i = 0; i < 4; ++i)
            #pragma unroll
            for (int j = 0; j < 4; ++j)
                acc[i][j] = __builtin_amdgcn_mfma_f32_16x16x32_bf16(
                    af[i], bfr[j], acc[i][j], 0, 0, 0);
    }

    // C/D layout: col = lane&15, row = (lane>>4)*4 + reg
    const int rb = m0 + wm + ((lane >> 4) << 2);
    const int cb = n0 + wn + (lane & 15);
    #pragma unroll
    for (int i = 0; i < 4; ++i)
        #pragma unroll
        for (int j = 0; j < 4; ++j)
            #pragma unroll
            for (int r = 0; r < 4; ++r)
                C[(size_t)(rb + i * 16 + r) * N + cb + j * 16] = acc[i][j][r];
}

// ---------------------------------------------------------------------------
// Generic fp32 tiled GEMM (kept for GEMM2/GEMM3). EPI=1: softplus(acc+bias).
// ---------------------------------------------------------------------------
template<int EPI>
__global__ __launch_bounds__(256) void gemm64(
    const float* __restrict__ A, int lda,
    const float* __restrict__ B, int ldb,
    float* __restrict__ C, int ldc,
    int M, int N, int K, const float* __restrict__ bias)
{
    __shared__ float AsT[16][68];
    __shared__ float Bs[16][68];

    const int tid = threadIdx.x;
    const int tx  = tid & 15;
    const int ty  = tid >> 4;
    const int m0  = blockIdx.y * 64;
    const int n0  = blockIdx.x * 64;

    const int ar = tid >> 2;
    const int ak = (tid & 3) * 4;
    const int bk = tid >> 4;
    const int bn = (tid & 15) * 4;

    float acc[4][4] = {};

    for (int k0 = 0; k0 < K; k0 += 16) {
        float4 av = *(const float4*)(A + (size_t)(m0 + ar) * lda + (k0 + ak));
        float4 bv;
        if (n0 + 64 <= N) {
            bv = *(const float4*)(B + (size_t)(k0 + bk) * ldb + (n0 + bn));
        } else {
            bv.x = (n0 + bn + 0 < N) ? B[(size_t)(k0 + bk) * ldb + n0 + bn + 0] : 0.f;
            bv.y = (n0 + bn + 1 < N) ? B[(size_t)(k0 + bk) * ldb + n0 + bn + 1] : 0.f;
            bv.z = (n0 + bn + 2 < N) ? B[(size_t)(k0 + bk) * ldb + n0 + bn + 2] : 0.f;
            bv.w = (n0 + bn + 3 < N) ? B[(size_t)(k0 + bk) * ldb + n0 + bn + 3] : 0.f;
        }
        __syncthreads();
        AsT[ak + 0][ar] = av.x;
        AsT[ak + 1][ar] = av.y;
        AsT[ak + 2][ar] = av.z;
        AsT[ak + 3][ar] = av.w;
        *(float4*)&Bs[bk][bn] = bv;
        __syncthreads();

        #pragma unroll
        for (int kk = 0; kk < 16; ++kk) {
            float4 a = *(const float4*)&AsT[kk][ty * 4];
            float4 b = *(const float4*)&Bs[kk][tx * 4];
            float aa[4] = {a.x, a.y, a.z, a.w};
            float bb[4] = {b.x, b.y, b.z, b.w};
            #pragma unroll
            for (int i = 0; i < 4; ++i)
                #pragma unroll
                for (int j = 0; j < 4; ++j)
                    acc[i][j] += aa[i] * bb[j];
        }
    }

    #pragma unroll
    for (int i = 0; i < 4; ++i) {
        int row = m0 + ty * 4 + i;
        #pragma unroll
        for (int j = 0; j < 4; ++j) {
            int col = n0 + tx * 4 + j;
            if (col < N) {
                float v = acc[i][j];
                if (EPI == 1) {
                    v += bias[col];
                    v = (v > 20.f) ? v : log1pf(expf(v));
                }
                C[(size_t)row * ldc + col] = v;
            }
        }
    }
}

// ---------------------------------------------------------------------------
// Causal depthwise conv (K=4) + SiLU.
// ---------------------------------------------------------------------------
__global__ __launch_bounds__(256) void conv_silu_k(
    const float* __restrict__ xz, const float* __restrict__ w_conv,
    const float* __restrict__ b_conv, float* __restrict__ uconv)
{
    int idx   = blockIdx.x * 256 + threadIdx.x;
    int d     = idx & (DIN - 1);
    int token = idx >> 11;
    int t     = token & (L_SEQ - 1);

    float acc = b_conv[d];
    #pragma unroll
    for (int k = 0; k < 4; ++k) {
        int tt = t - 3 + k;
        if (tt >= 0)
            acc += xz[(size_t)(token - 3 + k) * 4096 + d] * w_conv[d * 4 + k];
    }
    float s = acc / (1.f + expf(-acc));
    uconv[(size_t)token * DIN + d] = s;
}

// ---------------------------------------------------------------------------
// Chunked selective scan, pass 1.
// ---------------------------------------------------------------------------
__global__ __launch_bounds__(64) void scan_part1(
    const float* __restrict__ xz,
    const float* __restrict__ uconv,
    const float* __restrict__ dbc,
    const float* __restrict__ A_log,
    float* __restrict__ c_out,
    float* __restrict__ dsum_out)
{
    int chunk = blockIdx.x & 31;
    int dg    = (blockIdx.x >> 5) & 31;
    int b     = blockIdx.x >> 10;
    int tid   = threadIdx.x;
    int d     = dg * 64 + tid;

    __shared__ float sDelta[SCHUNK][64];
    __shared__ float sU[SCHUNK][64];
    __shared__ float sB[SCHUNK][16];

    float An[NST];
    #pragma unroll
    for (int n = 0; n < NST; ++n) An[n] = -expf(A_log[(size_t)d * NST + n]);

    float h[NST];
    #pragma unroll
    for (int n = 0; n < NST; ++n) h[n] = 0.f;
    float dsum = 0.f;

    const size_t tokbase = (size_t)b * L_SEQ + (size_t)chunk * CLEN;

    for (int t0 = 0; t0 < CLEN; t0 += SCHUNK) {
        __syncthreads();
        #pragma unroll
        for (int i = 0; i < SCHUNK; ++i) {
            size_t tok = tokbase + t0 + i;
            sDelta[i][tid] = xz[tok * 4096 + dg * 64 + tid];
            sU[i][tid]     = uconv[tok * 2048 + dg * 64 + tid];
        }
        #pragma unroll
        for (int i = 0; i < SCHUNK * 16 / 64; ++i) {
            int e = i * 64 + tid;
            int s = e >> 4, n = e & 15;
            sB[s][n] = dbc[(tokbase + t0 + s) * 96 + RRANK + n];
        }
        __syncthreads();

        #pragma unroll 4
        for (int s = 0; s < SCHUNK; ++s) {
            float delta = sDelta[s][tid];
            float u     = sU[s][tid];
            float du    = delta * u;
            dsum += delta;
            float bv[NST];
            #pragma unroll
            for (int q = 0; q < 4; ++q)
                *(float4*)&bv[q * 4] = ((const float4*)sB[s])[q];
            #pragma unroll
            for (int n = 0; n < NST; ++n)
                h[n] = h[n] * __expf(delta * An[n]) + du * bv[n];
        }
    }

    size_t base = (((size_t)b * DIN + d) * GCHUNK + chunk) * NST;
    #pragma unroll
    for (int q = 0; q < 4; ++q)
        *(float4*)&c_out[base + q * 4] = make_float4(h[q*4], h[q*4+1], h[q*4+2], h[q*4+3]);
    dsum_out[((size_t)b * DIN + d) * GCHUNK + chunk] = dsum;
}

// ---------------------------------------------------------------------------
// Pass 2: chunk-summary scan.
// ---------------------------------------------------------------------------
__global__ __launch_bounds__(256) void scan_part2(
    const float* __restrict__ c_in,
    const float* __restrict__ dsum_in,
    const float* __restrict__ A_log,
    float* __restrict__ h_start)
{
    int idx = blockIdx.x * 256 + threadIdx.x;
    int n   = idx & 15;
    int d   = (idx >> 4) & (DIN - 1);
    int b   = idx >> 15;

    float An = -expf(A_log[(size_t)d * NST + n]);
    size_t cb = ((size_t)b * DIN + d) * GCHUNK;

    float h = 0.f;
    for (int ch = 0; ch < GCHUNK; ++ch) {
        h_start[(cb + ch) * NST + n] = h;
        float dA = __expf(An * dsum_in[cb + ch]);
        h = h * dA + c_in[(cb + ch) * NST + n];
    }
}

// ---------------------------------------------------------------------------
// Pass 3: re-run chunks from h_start, y + gating epilogue.
// ---------------------------------------------------------------------------
__global__ __launch_bounds__(64) void scan_part3(
    const float* __restrict__ xz,
    float* __restrict__ uconv,
    const float* __restrict__ dbc,
    const float* __restrict__ A_log,
    const float* __restrict__ Dp,
    const float* __restrict__ h_start)
{
    int chunk = blockIdx.x & 31;
    int dg    = (blockIdx.x >> 5) & 31;
    int b     = blockIdx.x >> 10;
    int tid   = threadIdx.x;
    int d     = dg * 64 + tid;

    __shared__ float sDelta[SCHUNK][64];
    __shared__ float sU[SCHUNK][64];
    __shared__ float sZ[SCHUNK][64];
    __shared__ float sBC[SCHUNK][32];

    float An[NST];
    #pragma unroll
    for (int n = 0; n < NST; ++n) An[n] = -expf(A_log[(size_t)d * NST + n]);
    float Dd = Dp[d];

    float h[NST];
    size_t hb = (((size_t)b * DIN + d) * GCHUNK + chunk) * NST;
    #pragma unroll
    for (int q = 0; q < 4; ++q) {
        float4 v = *(const float4*)&h_start[hb + q * 4];
        h[q*4] = v.x; h[q*4+1] = v.y; h[q*4+2] = v.z; h[q*4+3] = v.w;
    }

    const size_t tokbase = (size_t)b * L_SEQ + (size_t)chunk * CLEN;

    for (int t0 = 0; t0 < CLEN; t0 += SCHUNK) {
        __syncthreads();
        #pragma unroll
        for (int i = 0; i < SCHUNK; ++i) {
            size_t tok = tokbase + t0 + i;
            sDelta[i][tid] = xz[tok * 4096 + dg * 64 + tid];
            sU[i][tid]     = uconv[tok * 2048 + dg * 64 + tid];
            sZ[i][tid]     = xz[tok * 4096 + 2048 + dg * 64 + tid];
        }
        #pragma unroll
        for (int i = 0; i < SCHUNK * 32 / 64; ++i) {
            int e = i * 64 + tid;
            int s = e >> 5, cc = e & 31;
            sBC[s][cc] = dbc[(tokbase + t0 + s) * 96 + RRANK + cc];
        }
        __syncthreads();

        for (int s = 0; s < SCHUNK; ++s) {
            float delta = sDelta[s][tid];
            float u     = sU[s][tid];
            float du    = delta * u;
            float bc[32];
            #pragma unroll
            for (int q = 0; q < 8; ++q)
                *(float4*)&bc[q * 4] = ((const float4*)sBC[s])[q];
            float y = 0.f;
            #pragma unroll
            for (int n = 0; n < NST; ++n) {
                float dA = __expf(delta * An[n]);
                h[n] = h[n] * dA + du * bc[n];
                y += h[n] * bc[16 + n];
            }
            float z  = sZ[s][tid];
            float sz = z / (1.f + __expf(-z));
            uconv[(tokbase + t0 + s) * 2048 + d] = (y + u * Dd) * sz;
        }
    }
}

// ---------------------------------------------------------------------------
// LayerNorm over DM + residual.
// ---------------------------------------------------------------------------
__global__ __launch_bounds__(256) void ln_k(
    const float* __restrict__ outpre, const float* __restrict__ x,
    const float* __restrict__ gamma, const float* __restrict__ beta,
    float* __restrict__ out)
{
    int row = blockIdx.x;
    int tid = threadIdx.x;
    const float* rp = outpre + (size_t)row * DMOD;
    float4 v = ((const float4*)rp)[tid];

    float s  = v.x + v.y + v.z + v.w;
    float s2 = v.x * v.x + v.y * v.y + v.z * v.z + v.w * v.w;
    #pragma unroll
    for (int off = 32; off > 0; off >>= 1) {
        s  += __shfl_down(s, off);
        s2 += __shfl_down(s2, off);
    }
    __shared__ float ws[4], ws2[4];
    int wave = tid >> 6, lane = tid & 63;
    if (lane == 0) { ws[wave] = s; ws2[wave] = s2; }
    __syncthreads();
    if (tid == 0) {
        float ts = 0.f, ts2 = 0.f;
        #pragma unroll
        for (int w = 0; w < 4; ++w) { ts += ws[w]; ts2 += ws2[w]; }
        ws[0] = ts; ws2[0] = ts2;
    }
    __syncthreads();
    float mu  = ws[0] * (1.f / DMOD);
    float var = ws2[0] * (1.f / DMOD) - mu * mu;
    float rs  = rsqrtf(var + 1e-5f);

    float4 g  = ((const float4*)gamma)[tid];
    float4 be = ((const float4*)beta)[tid];
    float4 xr = ((const float4*)(x + (size_t)row * DMOD))[tid];
    float4 o;
    o.x = (v.x - mu) * rs * g.x + be.x + xr.x;
    o.y = (v.y - mu) * rs * g.y + be.y + xr.y;
    o.z = (v.z - mu) * rs * g.z + be.z + xr.z;
    o.w = (v.w - mu) * rs * g.w + be.w + xr.w;
    ((float4*)(out + (size_t)row * DMOD))[tid] = o;
}

// ---------------------------------------------------------------------------
extern "C" void kernel_launch(void* const* d_in, const int* in_sizes, int n_in,
                              void* d_out, int out_size, void* d_ws, size_t ws_size,
                              hipStream_t stream)
{
    const float* x      = (const float*)d_in[0];
    const float* W_in   = (const float*)d_in[1];
    const float* w_conv = (const float*)d_in[2];
    const float* b_conv = (const float*)d_in[3];
    const float* W_x    = (const float*)d_in[4];
    const float* W_dt   = (const float*)d_in[5];
    const float* b_dt   = (const float*)d_in[6];
    const float* A_log  = (const float*)d_in[7];
    const float* Dp     = (const float*)d_in[8];
    const float* W_out  = (const float*)d_in[9];
    const float* gamma  = (const float*)d_in[10];
    const float* beta   = (const float*)d_in[11];
    float* out = (float*)d_out;

    char* ws = (char*)d_ws;
    const size_t MB = 1024 * 1024;
    float* xz     = (float*)(ws);                  // [4096][4096] fp32 (64 MB)
    float* uconv  = (float*)(ws + 64 * MB);        // [4096][2048] fp32 (32 MB)
    float* dbc    = (float*)(ws + 96 * MB);        // [4096][96]  (1.5 MB)
    float* dsum   = (float*)(ws + (97 * MB + 512 * 1024)); // (0.5 MB)
    float* c_buf  = (float*)(ws + 98 * MB);        // 8 MB   (scan phase)
    float* hstart = (float*)(ws + 106 * MB);       // 8 MB   (scan phase)
    // pre-GEMM1 phase (dead before scan writes c_buf/hstart):
    ushort* xb    = (ushort*)(ws + 98 * MB);       // [4096][1024] bf16 (8 MB)
    ushort* Wib   = (ushort*)(ws + 106 * MB);      // [4096][1024] bf16 (8 MB)
    // post-scan phase (xz dead after scan_part3):
    ushort* yb    = (ushort*)(ws);                 // [4096][2048] bf16 (16 MB)
    ushort* Wob   = (ushort*)(ws + 16 * MB);       // [1024][2048] bf16 (4 MB)
    float* outpre = (float*)(ws + 32 * MB);        // [4096][1024] fp32 (16 MB)

    dim3 blk(256);

    // 0a. x -> bf16
    cast_bf16_k<<<dim3(NTOK * DMOD / 2048), blk, 0, stream>>>(x, xb);
    // 0b. W_in (1024 x 4096) -> W_in^T bf16 (4096 x 1024)
    tcast_k<<<dim3(4096 / 32, 1024 / 32), blk, 0, stream>>>(W_in, Wib, 1024, 4096);
    // 1. xz = x @ W_in   (MFMA bf16)
    gemm_mfma<<<dim3(4096 / 128, 4096 / 128), blk, 0, stream>>>(
        xb, Wib, xz, 4096, 4096, 1024);
    // 2. u = silu(causal_conv(u)) -> uconv
    conv_silu_k<<<dim3(NTOK * DIN / 256), blk, 0, stream>>>(xz, w_conv, b_conv, uconv);
    // 3. dbc = u @ W_x  (fp32)
    gemm64<0><<<dim3(2, 64), blk, 0, stream>>>(uconv, 2048, W_x, 96, dbc, 96,
                                               4096, 96, 2048, nullptr);
    // 4. delta = softplus(dt @ W_dt + b_dt) -> u-half of xz (fp32)
    gemm64<1><<<dim3(32, 64), blk, 0, stream>>>(dbc, 96, W_dt, 2048, xz, 4096,
                                                4096, 2048, 64, b_dt);
    // 5. chunked selective scan -> y overwrites uconv
    scan_part1<<<dim3(NBATCH * 32 * GCHUNK), dim3(64), 0, stream>>>(
        xz, uconv, dbc, A_log, c_buf, dsum);
    scan_part2<<<dim3(NBATCH * DIN * NST / 256), blk, 0, stream>>>(
        c_buf, dsum, A_log, hstart);
    scan_part3<<<dim3(NBATCH * 32 * GCHUNK), dim3(64), 0, stream>>>(
        xz, uconv, dbc, A_log, Dp, hstart);
    // 6a. y -> bf16 (xz region is dead now)
    cast_bf16_k<<<dim3(NTOK * DIN / 2048), blk, 0, stream>>>(uconv, yb);
    // 6b. W_out (2048 x 1024) -> W_out^T bf16 (1024 x 2048)
    tcast_k<<<dim3(1024 / 32, 2048 / 32), blk, 0, stream>>>(W_out, Wob, 2048, 1024);
    // 6c. out_pre = y @ W_out  (MFMA bf16)
    gemm_mfma<<<dim3(1024 / 128, 4096 / 128), blk, 0, stream>>>(
        yb, Wob, outpre, 4096, 1024, 2048);
    // 7. LayerNorm + residual
    ln_k<<<dim3(NTOK), blk, 0, stream>>>(outpre, x, gamma, beta, out);
}

// Round 4
// 447.271 us; speedup vs baseline: 4.1889x; 1.2589x over previous
//
#include <hip/hip_runtime.h>
#include <math.h>

#define L_SEQ 2048
#define DMOD  1024
#define DIN   2048
#define NBATCH 2
#define NTOK  (NBATCH * L_SEQ)   // 4096 tokens
#define NST   16
#define RRANK 64

#define GCHUNK 32                 // chunks along L
#define CLEN   (L_SEQ / GCHUNK)   // 64 steps per chunk
#define SCHUNK 16                 // LDS staging depth

typedef __attribute__((ext_vector_type(8))) short  short8;   // 8 bf16
typedef __attribute__((ext_vector_type(4))) float  f32x4;

// round-to-nearest-even fp32 -> bf16
__device__ __forceinline__ ushort f2bf(float f) {
    unsigned u = __float_as_uint(f);
    u += 0x7fffu + ((u >> 16) & 1u);
    return (ushort)(u >> 16);
}

// ---------------------------------------------------------------------------
// Flat cast fp32 -> bf16, 8 elements/thread.
// ---------------------------------------------------------------------------
__global__ __launch_bounds__(256) void cast_bf16_k(
    const float* __restrict__ src, ushort* __restrict__ dst)
{
    int i = (blockIdx.x * 256 + threadIdx.x) * 8;
    float4 a = *(const float4*)(src + i);
    float4 b = *(const float4*)(src + i + 4);
    ushort4 o0 = make_ushort4(f2bf(a.x), f2bf(a.y), f2bf(a.z), f2bf(a.w));
    ushort4 o1 = make_ushort4(f2bf(b.x), f2bf(b.y), f2bf(b.z), f2bf(b.w));
    *(ushort4*)(dst + i)     = o0;
    *(ushort4*)(dst + i + 4) = o1;
}

// ---------------------------------------------------------------------------
// Transpose + cast: src fp32 [R][C] -> dst bf16 [C][R]. 32x32 LDS tile.
// ---------------------------------------------------------------------------
__global__ __launch_bounds__(256) void tcast_k(
    const float* __restrict__ src, ushort* __restrict__ dst, int R, int C)
{
    __shared__ float t[32][33];
    int tx  = threadIdx.x & 31;
    int ty  = threadIdx.x >> 5;        // 0..7
    int c0  = blockIdx.x * 32;
    int r0  = blockIdx.y * 32;
    #pragma unroll
    for (int i = 0; i < 4; ++i)
        t[ty + i * 8][tx] = src[(size_t)(r0 + ty + i * 8) * C + c0 + tx];
    __syncthreads();
    #pragma unroll
    for (int i = 0; i < 4; ++i)
        dst[(size_t)(c0 + ty + i * 8) * R + r0 + tx] = f2bf(t[tx][ty + i * 8]);
}

// ---------------------------------------------------------------------------
// bf16 MFMA GEMM: C(M,N) fp32 = A(M,K) @ Bt(N,K)^T, 128x128 tile, BK=32,
// 256 threads = 4 waves, each wave 64x64 via 4x4 grid of 16x16x32 MFMAs.
// ---------------------------------------------------------------------------
#define LDK 40   // padded halfs per LDS row (80 B: 16B-aligned, 2-way banks = free)
__global__ __launch_bounds__(256) void gemm_mfma(
    const ushort* __restrict__ A,   // [M][K] bf16
    const ushort* __restrict__ Bt,  // [N][K] bf16
    float* __restrict__ C,          // [M][N] fp32
    int M, int N, int K)
{
    __shared__ ushort As[128 * LDK];
    __shared__ ushort Bs[128 * LDK];

    const int tid  = threadIdx.x;
    const int wave = tid >> 6;
    const int lane = tid & 63;
    const int wm   = (wave & 1) * 64;
    const int wn   = (wave >> 1) * 64;
    const int m0   = blockIdx.y * 128;
    const int n0   = blockIdx.x * 128;

    const int srow  = tid >> 2;         // 0..63
    const int skoff = (tid & 3) * 8;    // 0,8,16,24 halfs

    f32x4 acc[4][4];
    #pragma unroll
    for (int i = 0; i < 4; ++i)
        #pragma unroll
        for (int j = 0; j < 4; ++j)
            acc[i][j] = (f32x4){0.f, 0.f, 0.f, 0.f};

    const int lrow = lane & 15;
    const int kq   = (lane >> 4) * 8;

    for (int k0 = 0; k0 < K; k0 += 32) {
        uint4 a0 = *(const uint4*)(A  + (size_t)(m0 + srow)      * K + k0 + skoff);
        uint4 a1 = *(const uint4*)(A  + (size_t)(m0 + 64 + srow) * K + k0 + skoff);
        uint4 b0 = *(const uint4*)(Bt + (size_t)(n0 + srow)      * K + k0 + skoff);
        uint4 b1 = *(const uint4*)(Bt + (size_t)(n0 + 64 + srow) * K + k0 + skoff);
        __syncthreads();
        *(uint4*)&As[(srow)      * LDK + skoff] = a0;
        *(uint4*)&As[(64 + srow) * LDK + skoff] = a1;
        *(uint4*)&Bs[(srow)      * LDK + skoff] = b0;
        *(uint4*)&Bs[(64 + srow) * LDK + skoff] = b1;
        __syncthreads();

        short8 af[4], bfr[4];
        #pragma unroll
        for (int i = 0; i < 4; ++i) {
            af[i]  = *(const short8*)&As[(wm + i * 16 + lrow) * LDK + kq];
            bfr[i] = *(const short8*)&Bs[(wn + i * 16 + lrow) * LDK + kq];
        }
        #pragma unroll
        for (int i = 0; i < 4; ++i)
            #pragma unroll
            for (int j = 0; j < 4; ++j)
                acc[i][j] = __builtin_amdgcn_mfma_f32_16x16x32_bf16(
                    af[i], bfr[j], acc[i][j], 0, 0, 0);
    }

    // C/D layout: col = lane&15, row = (lane>>4)*4 + reg
    const int rb = m0 + wm + ((lane >> 4) << 2);
    const int cb = n0 + wn + (lane & 15);
    #pragma unroll
    for (int i = 0; i < 4; ++i)
        #pragma unroll
        for (int j = 0; j < 4; ++j)
            #pragma unroll
            for (int r = 0; r < 4; ++r)
                C[(size_t)(rb + i * 16 + r) * N + cb + j * 16] = acc[i][j][r];
}

// ---------------------------------------------------------------------------
// GEMM2 split-K: part[ks] = uconv[:, ks*256:(ks+1)*256] @ W_x[slice].
// Grid (8, 64): ks x m-tile(64 rows). 4 LDS stages of 64 k each.
// ---------------------------------------------------------------------------
#define G2_KSPLIT 8
#define G2_KC     256
#define G2_STAGE  64
__global__ __launch_bounds__(256) void gemm2_splitk(
    const float* __restrict__ A,    // [4096][2048] = uconv
    const float* __restrict__ B,    // [2048][96]   = W_x
    float* __restrict__ part)       // [8][4096][96]
{
    __shared__ float AsT[G2_STAGE][65];   // [k][m], odd pad: conflict-free reads
    __shared__ float Bs[G2_STAGE][96];

    const int tid = threadIdx.x;
    const int ks  = blockIdx.x;
    const int m0  = blockIdx.y * 64;
    const int tx  = tid & 15;       // 6 cols each
    const int ty  = tid >> 4;       // 4 rows each

    float acc[4][6] = {};

    for (int st = 0; st < G2_KC / G2_STAGE; ++st) {
        const int k0 = ks * G2_KC + st * G2_STAGE;
        float4 av[4];
        #pragma unroll
        for (int i = 0; i < 4; ++i) {
            int idx = tid + 256 * i;            // 0..1023
            int row = idx >> 4, c4 = idx & 15;
            av[i] = *(const float4*)(A + (size_t)(m0 + row) * 2048 + k0 + c4 * 4);
        }
        float4 bv[6];
        #pragma unroll
        for (int i = 0; i < 6; ++i) {
            int idx = tid + 256 * i;            // 0..1535
            int row = idx / 24, c4 = idx % 24;
            bv[i] = *(const float4*)(B + (size_t)(k0 + row) * 96 + c4 * 4);
        }
        __syncthreads();
        #pragma unroll
        for (int i = 0; i < 4; ++i) {
            int idx = tid + 256 * i;
            int row = idx >> 4, c4 = idx & 15;
            AsT[c4 * 4 + 0][row] = av[i].x;
            AsT[c4 * 4 + 1][row] = av[i].y;
            AsT[c4 * 4 + 2][row] = av[i].z;
            AsT[c4 * 4 + 3][row] = av[i].w;
        }
        #pragma unroll
        for (int i = 0; i < 6; ++i) {
            int idx = tid + 256 * i;
            int row = idx / 24, c4 = idx % 24;
            *(float4*)&Bs[row][c4 * 4] = bv[i];
        }
        __syncthreads();

        #pragma unroll 8
        for (int kk = 0; kk < G2_STAGE; ++kk) {
            float a[4], b[6];
            #pragma unroll
            for (int r = 0; r < 4; ++r) a[r] = AsT[kk][ty * 4 + r];
            #pragma unroll
            for (int c = 0; c < 6; ++c) b[c] = Bs[kk][tx * 6 + c];
            #pragma unroll
            for (int r = 0; r < 4; ++r)
                #pragma unroll
                for (int c = 0; c < 6; ++c)
                    acc[r][c] += a[r] * b[c];
        }
    }

    float* po = part + (size_t)ks * NTOK * 96;
    #pragma unroll
    for (int r = 0; r < 4; ++r)
        #pragma unroll
        for (int c = 0; c < 6; ++c)
            po[(size_t)(m0 + ty * 4 + r) * 96 + tx * 6 + c] = acc[r][c];
}

// ---------------------------------------------------------------------------
// GEMM2 reduce: dbc = sum over 8 k-slices. float4 per thread.
// ---------------------------------------------------------------------------
__global__ __launch_bounds__(256) void gemm2_reduce(
    const float* __restrict__ part, float* __restrict__ dbc)
{
    int i = (blockIdx.x * 256 + threadIdx.x) * 4;   // over 4096*96
    float4 s = *(const float4*)(part + i);
    #pragma unroll
    for (int ks = 1; ks < G2_KSPLIT; ++ks) {
        float4 v = *(const float4*)(part + (size_t)ks * NTOK * 96 + i);
        s.x += v.x; s.y += v.y; s.z += v.z; s.w += v.w;
    }
    *(float4*)(dbc + i) = s;
}

// ---------------------------------------------------------------------------
// Generic fp32 tiled GEMM (kept for GEMM3). EPI=1: softplus(acc+bias).
// ---------------------------------------------------------------------------
template<int EPI>
__global__ __launch_bounds__(256) void gemm64(
    const float* __restrict__ A, int lda,
    const float* __restrict__ B, int ldb,
    float* __restrict__ C, int ldc,
    int M, int N, int K, const float* __restrict__ bias)
{
    __shared__ float AsT[16][68];
    __shared__ float Bs[16][68];

    const int tid = threadIdx.x;
    const int tx  = tid & 15;
    const int ty  = tid >> 4;
    const int m0  = blockIdx.y * 64;
    const int n0  = blockIdx.x * 64;

    const int ar = tid >> 2;
    const int ak = (tid & 3) * 4;
    const int bk = tid >> 4;
    const int bn = (tid & 15) * 4;

    float acc[4][4] = {};

    for (int k0 = 0; k0 < K; k0 += 16) {
        float4 av = *(const float4*)(A + (size_t)(m0 + ar) * lda + (k0 + ak));
        float4 bv;
        if (n0 + 64 <= N) {
            bv = *(const float4*)(B + (size_t)(k0 + bk) * ldb + (n0 + bn));
        } else {
            bv.x = (n0 + bn + 0 < N) ? B[(size_t)(k0 + bk) * ldb + n0 + bn + 0] : 0.f;
            bv.y = (n0 + bn + 1 < N) ? B[(size_t)(k0 + bk) * ldb + n0 + bn + 1] : 0.f;
            bv.z = (n0 + bn + 2 < N) ? B[(size_t)(k0 + bk) * ldb + n0 + bn + 2] : 0.f;
            bv.w = (n0 + bn + 3 < N) ? B[(size_t)(k0 + bk) * ldb + n0 + bn + 3] : 0.f;
        }
        __syncthreads();
        AsT[ak + 0][ar] = av.x;
        AsT[ak + 1][ar] = av.y;
        AsT[ak + 2][ar] = av.z;
        AsT[ak + 3][ar] = av.w;
        *(float4*)&Bs[bk][bn] = bv;
        __syncthreads();

        #pragma unroll
        for (int kk = 0; kk < 16; ++kk) {
            float4 a = *(const float4*)&AsT[kk][ty * 4];
            float4 b = *(const float4*)&Bs[kk][tx * 4];
            float aa[4] = {a.x, a.y, a.z, a.w};
            float bb[4] = {b.x, b.y, b.z, b.w};
            #pragma unroll
            for (int i = 0; i < 4; ++i)
                #pragma unroll
                for (int j = 0; j < 4; ++j)
                    acc[i][j] += aa[i] * bb[j];
        }
    }

    #pragma unroll
    for (int i = 0; i < 4; ++i) {
        int row = m0 + ty * 4 + i;
        #pragma unroll
        for (int j = 0; j < 4; ++j) {
            int col = n0 + tx * 4 + j;
            if (col < N) {
                float v = acc[i][j];
                if (EPI == 1) {
                    v += bias[col];
                    v = (v > 20.f) ? v : log1pf(expf(v));
                }
                C[(size_t)row * ldc + col] = v;
            }
        }
    }
}

// ---------------------------------------------------------------------------
// Causal depthwise conv (K=4) + SiLU.
// ---------------------------------------------------------------------------
__global__ __launch_bounds__(256) void conv_silu_k(
    const float* __restrict__ xz, const float* __restrict__ w_conv,
    const float* __restrict__ b_conv, float* __restrict__ uconv)
{
    int idx   = blockIdx.x * 256 + threadIdx.x;
    int d     = idx & (DIN - 1);
    int token = idx >> 11;
    int t     = token & (L_SEQ - 1);

    float acc = b_conv[d];
    #pragma unroll
    for (int k = 0; k < 4; ++k) {
        int tt = t - 3 + k;
        if (tt >= 0)
            acc += xz[(size_t)(token - 3 + k) * 4096 + d] * w_conv[d * 4 + k];
    }
    float s = acc / (1.f + expf(-acc));
    uconv[(size_t)token * DIN + d] = s;
}

// ---------------------------------------------------------------------------
// Chunked selective scan, pass 1.
// ---------------------------------------------------------------------------
__global__ __launch_bounds__(64) void scan_part1(
    const float* __restrict__ xz,
    const float* __restrict__ uconv,
    const float* __restrict__ dbc,
    const float* __restrict__ A_log,
    float* __restrict__ c_out,
    float* __restrict__ dsum_out)
{
    int chunk = blockIdx.x & 31;
    int dg    = (blockIdx.x >> 5) & 31;
    int b     = blockIdx.x >> 10;
    int tid   = threadIdx.x;
    int d     = dg * 64 + tid;

    __shared__ float sDelta[SCHUNK][64];
    __shared__ float sU[SCHUNK][64];
    __shared__ float sB[SCHUNK][16];

    float An[NST];
    #pragma unroll
    for (int n = 0; n < NST; ++n) An[n] = -expf(A_log[(size_t)d * NST + n]);

    float h[NST];
    #pragma unroll
    for (int n = 0; n < NST; ++n) h[n] = 0.f;
    float dsum = 0.f;

    const size_t tokbase = (size_t)b * L_SEQ + (size_t)chunk * CLEN;

    for (int t0 = 0; t0 < CLEN; t0 += SCHUNK) {
        __syncthreads();
        #pragma unroll
        for (int i = 0; i < SCHUNK; ++i) {
            size_t tok = tokbase + t0 + i;
            sDelta[i][tid] = xz[tok * 4096 + dg * 64 + tid];
            sU[i][tid]     = uconv[tok * 2048 + dg * 64 + tid];
        }
        #pragma unroll
        for (int i = 0; i < SCHUNK * 16 / 64; ++i) {
            int e = i * 64 + tid;
            int s = e >> 4, n = e & 15;
            sB[s][n] = dbc[(tokbase + t0 + s) * 96 + RRANK + n];
        }
        __syncthreads();

        #pragma unroll 4
        for (int s = 0; s < SCHUNK; ++s) {
            float delta = sDelta[s][tid];
            float u     = sU[s][tid];
            float du    = delta * u;
            dsum += delta;
            float bv[NST];
            #pragma unroll
            for (int q = 0; q < 4; ++q)
                *(float4*)&bv[q * 4] = ((const float4*)sB[s])[q];
            #pragma unroll
            for (int n = 0; n < NST; ++n)
                h[n] = h[n] * __expf(delta * An[n]) + du * bv[n];
        }
    }

    size_t base = (((size_t)b * DIN + d) * GCHUNK + chunk) * NST;
    #pragma unroll
    for (int q = 0; q < 4; ++q)
        *(float4*)&c_out[base + q * 4] = make_float4(h[q*4], h[q*4+1], h[q*4+2], h[q*4+3]);
    dsum_out[((size_t)b * DIN + d) * GCHUNK + chunk] = dsum;
}

// ---------------------------------------------------------------------------
// Pass 2: chunk-summary scan.
// ---------------------------------------------------------------------------
__global__ __launch_bounds__(256) void scan_part2(
    const float* __restrict__ c_in,
    const float* __restrict__ dsum_in,
    const float* __restrict__ A_log,
    float* __restrict__ h_start)
{
    int idx = blockIdx.x * 256 + threadIdx.x;
    int n   = idx & 15;
    int d   = (idx >> 4) & (DIN - 1);
    int b   = idx >> 15;

    float An = -expf(A_log[(size_t)d * NST + n]);
    size_t cb = ((size_t)b * DIN + d) * GCHUNK;

    float h = 0.f;
    for (int ch = 0; ch < GCHUNK; ++ch) {
        h_start[(cb + ch) * NST + n] = h;
        float dA = __expf(An * dsum_in[cb + ch]);
        h = h * dA + c_in[(cb + ch) * NST + n];
    }
}

// ---------------------------------------------------------------------------
// Pass 3: re-run chunks from h_start, y + gating epilogue.
// ---------------------------------------------------------------------------
__global__ __launch_bounds__(64) void scan_part3(
    const float* __restrict__ xz,
    float* __restrict__ uconv,
    const float* __restrict__ dbc,
    const float* __restrict__ A_log,
    const float* __restrict__ Dp,
    const float* __restrict__ h_start)
{
    int chunk = blockIdx.x & 31;
    int dg    = (blockIdx.x >> 5) & 31;
    int b     = blockIdx.x >> 10;
    int tid   = threadIdx.x;
    int d     = dg * 64 + tid;

    __shared__ float sDelta[SCHUNK][64];
    __shared__ float sU[SCHUNK][64];
    __shared__ float sZ[SCHUNK][64];
    __shared__ float sBC[SCHUNK][32];

    float An[NST];
    #pragma unroll
    for (int n = 0; n < NST; ++n) An[n] = -expf(A_log[(size_t)d * NST + n]);
    float Dd = Dp[d];

    float h[NST];
    size_t hb = (((size_t)b * DIN + d) * GCHUNK + chunk) * NST;
    #pragma unroll
    for (int q = 0; q < 4; ++q) {
        float4 v = *(const float4*)&h_start[hb + q * 4];
        h[q*4] = v.x; h[q*4+1] = v.y; h[q*4+2] = v.z; h[q*4+3] = v.w;
    }

    const size_t tokbase = (size_t)b * L_SEQ + (size_t)chunk * CLEN;

    for (int t0 = 0; t0 < CLEN; t0 += SCHUNK) {
        __syncthreads();
        #pragma unroll
        for (int i = 0; i < SCHUNK; ++i) {
            size_t tok = tokbase + t0 + i;
            sDelta[i][tid] = xz[tok * 4096 + dg * 64 + tid];
            sU[i][tid]     = uconv[tok * 2048 + dg * 64 + tid];
            sZ[i][tid]     = xz[tok * 4096 + 2048 + dg * 64 + tid];
        }
        #pragma unroll
        for (int i = 0; i < SCHUNK * 32 / 64; ++i) {
            int e = i * 64 + tid;
            int s = e >> 5, cc = e & 31;
            sBC[s][cc] = dbc[(tokbase + t0 + s) * 96 + RRANK + cc];
        }
        __syncthreads();

        for (int s = 0; s < SCHUNK; ++s) {
            float delta = sDelta[s][tid];
            float u     = sU[s][tid];
            float du    = delta * u;
            float bc[32];
            #pragma unroll
            for (int q = 0; q < 8; ++q)
                *(float4*)&bc[q * 4] = ((const float4*)sBC[s])[q];
            float y = 0.f;
            #pragma unroll
            for (int n = 0; n < NST; ++n) {
                float dA = __expf(delta * An[n]);
                h[n] = h[n] * dA + du * bc[n];
                y += h[n] * bc[16 + n];
            }
            float z  = sZ[s][tid];
            float sz = z / (1.f + __expf(-z));
            uconv[(tokbase + t0 + s) * 2048 + d] = (y + u * Dd) * sz;
        }
    }
}

// ---------------------------------------------------------------------------
// LayerNorm over DM + residual.
// ---------------------------------------------------------------------------
__global__ __launch_bounds__(256) void ln_k(
    const float* __restrict__ outpre, const float* __restrict__ x,
    const float* __restrict__ gamma, const float* __restrict__ beta,
    float* __restrict__ out)
{
    int row = blockIdx.x;
    int tid = threadIdx.x;
    const float* rp = outpre + (size_t)row * DMOD;
    float4 v = ((const float4*)rp)[tid];

    float s  = v.x + v.y + v.z + v.w;
    float s2 = v.x * v.x + v.y * v.y + v.z * v.z + v.w * v.w;
    #pragma unroll
    for (int off = 32; off > 0; off >>= 1) {
        s  += __shfl_down(s, off);
        s2 += __shfl_down(s2, off);
    }
    __shared__ float ws[4], ws2[4];
    int wave = tid >> 6, lane = tid & 63;
    if (lane == 0) { ws[wave] = s; ws2[wave] = s2; }
    __syncthreads();
    if (tid == 0) {
        float ts = 0.f, ts2 = 0.f;
        #pragma unroll
        for (int w = 0; w < 4; ++w) { ts += ws[w]; ts2 += ws2[w]; }
        ws[0] = ts; ws2[0] = ts2;
    }
    __syncthreads();
    float mu  = ws[0] * (1.f / DMOD);
    float var = ws2[0] * (1.f / DMOD) - mu * mu;
    float rs  = rsqrtf(var + 1e-5f);

    float4 g  = ((const float4*)gamma)[tid];
    float4 be = ((const float4*)beta)[tid];
    float4 xr = ((const float4*)(x + (size_t)row * DMOD))[tid];
    float4 o;
    o.x = (v.x - mu) * rs * g.x + be.x + xr.x;
    o.y = (v.y - mu) * rs * g.y + be.y + xr.y;
    o.z = (v.z - mu) * rs * g.z + be.z + xr.z;
    o.w = (v.w - mu) * rs * g.w + be.w + xr.w;
    ((float4*)(out + (size_t)row * DMOD))[tid] = o;
}

// ---------------------------------------------------------------------------
extern "C" void kernel_launch(void* const* d_in, const int* in_sizes, int n_in,
                              void* d_out, int out_size, void* d_ws, size_t ws_size,
                              hipStream_t stream)
{
    const float* x      = (const float*)d_in[0];
    const float* W_in   = (const float*)d_in[1];
    const float* w_conv = (const float*)d_in[2];
    const float* b_conv = (const float*)d_in[3];
    const float* W_x    = (const float*)d_in[4];
    const float* W_dt   = (const float*)d_in[5];
    const float* b_dt   = (const float*)d_in[6];
    const float* A_log  = (const float*)d_in[7];
    const float* Dp     = (const float*)d_in[8];
    const float* W_out  = (const float*)d_in[9];
    const float* gamma  = (const float*)d_in[10];
    const float* beta   = (const float*)d_in[11];
    float* out = (float*)d_out;

    char* ws = (char*)d_ws;
    const size_t MB = 1024 * 1024;
    float* xz     = (float*)(ws);                  // [4096][4096] fp32 (64 MB)
    float* uconv  = (float*)(ws + 64 * MB);        // [4096][2048] fp32 (32 MB)
    float* dbc    = (float*)(ws + 96 * MB);        // [4096][96]  (1.5 MB)
    float* dsum   = (float*)(ws + (97 * MB + 512 * 1024)); // (0.5 MB)
    float* c_buf  = (float*)(ws + 98 * MB);        // 8 MB   (scan phase)
    float* hstart = (float*)(ws + 106 * MB);       // 8 MB   (scan phase)
    // pre-GEMM1 phase (dead after gemm_mfma #1):
    ushort* xb    = (ushort*)(ws + 98 * MB);       // [4096][1024] bf16 (8 MB)
    ushort* Wib   = (ushort*)(ws + 106 * MB);      // [4096][1024] bf16 (8 MB)
    // GEMM2 phase (xb/Wib dead; consumed before scan writes c_buf):
    float* g2part = (float*)(ws + 98 * MB);        // [8][4096][96] (12.6 MB)
    // post-scan phase (xz dead after scan_part3):
    ushort* yb    = (ushort*)(ws);                 // [4096][2048] bf16 (16 MB)
    ushort* Wob   = (ushort*)(ws + 16 * MB);       // [1024][2048] bf16 (4 MB)
    float* outpre = (float*)(ws + 32 * MB);        // [4096][1024] fp32 (16 MB)

    dim3 blk(256);

    // 0a. x -> bf16
    cast_bf16_k<<<dim3(NTOK * DMOD / 2048), blk, 0, stream>>>(x, xb);
    // 0b. W_in (1024 x 4096) -> W_in^T bf16 (4096 x 1024)
    tcast_k<<<dim3(4096 / 32, 1024 / 32), blk, 0, stream>>>(W_in, Wib, 1024, 4096);
    // 1. xz = x @ W_in   (MFMA bf16)
    gemm_mfma<<<dim3(4096 / 128, 4096 / 128), blk, 0, stream>>>(
        xb, Wib, xz, 4096, 4096, 1024);
    // 2. u = silu(causal_conv(u)) -> uconv
    conv_silu_k<<<dim3(NTOK * DIN / 256), blk, 0, stream>>>(xz, w_conv, b_conv, uconv);
    // 3. dbc = u @ W_x  (fp32 split-K + reduce)
    gemm2_splitk<<<dim3(G2_KSPLIT, 64), blk, 0, stream>>>(uconv, W_x, g2part);
    gemm2_reduce<<<dim3(NTOK * 96 / 4 / 256), blk, 0, stream>>>(g2part, dbc);
    // 4. delta = softplus(dt @ W_dt + b_dt) -> u-half of xz (fp32)
    gemm64<1><<<dim3(32, 64), blk, 0, stream>>>(dbc, 96, W_dt, 2048, xz, 4096,
                                                4096, 2048, 64, b_dt);
    // 5. chunked selective scan -> y overwrites uconv
    scan_part1<<<dim3(NBATCH * 32 * GCHUNK), dim3(64), 0, stream>>>(
        xz, uconv, dbc, A_log, c_buf, dsum);
    scan_part2<<<dim3(NBATCH * DIN * NST / 256), blk, 0, stream>>>(
        c_buf, dsum, A_log, hstart);
    scan_part3<<<dim3(NBATCH * 32 * GCHUNK), dim3(64), 0, stream>>>(
        xz, uconv, dbc, A_log, Dp, hstart);
    // 6a. y -> bf16 (xz region is dead now)
    cast_bf16_k<<<dim3(NTOK * DIN / 2048), blk, 0, stream>>>(uconv, yb);
    // 6b. W_out (2048 x 1024) -> W_out^T bf16 (1024 x 2048)
    tcast_k<<<dim3(1024 / 32, 2048 / 32), blk, 0, stream>>>(W_out, Wob, 2048, 1024);
    // 6c. out_pre = y @ W_out  (MFMA bf16)
    gemm_mfma<<<dim3(1024 / 128, 4096 / 128), blk, 0, stream>>>(
        yb, Wob, outpre, 4096, 1024, 2048);
    // 7. LayerNorm + residual
    ln_k<<<dim3(NTOK), blk, 0, stream>>>(outpre, x, gamma, beta, out);
}